// Round 10
// baseline (106.765 us; speedup 1.0000x reference)
//
#include <hip/hip_runtime.h>

#define NB 8
#define DM 256
#define FD 96

using half8 = _Float16 __attribute__((ext_vector_type(8)));
using f32x4 = float __attribute__((ext_vector_type(4)));

__device__ __forceinline__ float clamp01(float x) { return fminf(fmaxf(x, 0.0f), 1.0f); }

// ---------------------------------------------------------------------------
// Kernel 0: precompute B = lin_w^T as f16 MFMA fragments into d_ws (48 KB).
// ---------------------------------------------------------------------------
__global__ void bprep_kernel(const float* __restrict__ lin_w,
                             _Float16* __restrict__ Bpre)
{
    const int fb = blockIdx.x * 256 + threadIdx.x;     // 0..3071
    const int ks = fb >> 10, nbv = (fb >> 6) & 15, ll = fb & 63;
    const float* lwrow = lin_w + (size_t)(nbv * 16 + (ll & 15)) * FD
                               + (ks * 32 + 4 * (ll >> 4));
    float4 lo = *reinterpret_cast<const float4*>(lwrow);
    float4 hi = *reinterpret_cast<const float4*>(lwrow + 16);
    half8 v;
    v[0] = (_Float16)lo.x; v[1] = (_Float16)lo.y; v[2] = (_Float16)lo.z; v[3] = (_Float16)lo.w;
    v[4] = (_Float16)hi.x; v[5] = (_Float16)hi.y; v[6] = (_Float16)hi.z; v[7] = (_Float16)hi.w;
    *reinterpret_cast<half8*>(Bpre + (size_t)fb * 8) = v;
}

// ---------------------------------------------------------------------------
// Kernel A: sim with 2 lanes per position (r9 structure, unchanged math).
// __launch_bounds__(256, 4): occupancy buckets are VGPR {<=64:8, <=128:4,
// <=256:2 waves/SIMD}. r9 used (256,1) -> compiler free to exceed 128 VGPR
// -> stuck at 2 waves/SIMD, nullifying the 2-lane split. In-loop live set
// here is ~100 floats (h 32 + W 32 + nb 16 + temps), so the 128 cap is safe
// (r6's spill collapse happened with ~160 live under the same cap).
// ---------------------------------------------------------------------------
__global__ __launch_bounds__(256, 4) void bio_sim_kernel(
    const int* __restrict__ bits,
    const float* __restrict__ stim_in,
    const float* __restrict__ Winit,
    const int* __restrict__ steps_ptr,
    float* __restrict__ out_h,
    float* __restrict__ out_W,
    int npos)
{
    const int tid  = threadIdx.x;
    const int gtid = blockIdx.x * 256 + tid;
    const int pos  = gtid >> 1;
    const int sub  = gtid & 1;
    const int steps = steps_ptr[0];

    float h[8][4];   // local order: 0..3 own half, 4..7 partner half
    float W[4][8];   // own 4 rows x 8 local cols

    // ---- decode own 4 blocks
    const int4* bp = reinterpret_cast<const int4*>(bits + (size_t)pos * 64 + sub * 32);
    #pragma unroll
    for (int b = 0; b < 4; ++b) {
        int4 lo = bp[2 * b + 0];
        int4 hi = bp[2 * b + 1];
        h[b][0] = (float)(lo.x * 2 + lo.y) / 3.0f;
        h[b][1] = (float)(lo.z * 2 + lo.w) / 3.0f;
        h[b][2] = (float)(hi.x * 2 + hi.y) / 3.0f;
        h[b][3] = (float)(hi.z * 2 + hi.w) / 3.0f;
    }
    #pragma unroll
    for (int b = 0; b < 4; ++b)
        #pragma unroll
        for (int c = 0; c < 4; ++c)
            h[4 + b][c] = __shfl_xor(h[b][c], 1, 64);

    // ---- own W rows, local col order (own half cols first), zero diag
    const int co_own = sub * 4;          // global col offset of own half
    const int co_oth = 4 - sub * 4;      // global col offset of partner half
    #pragma unroll
    for (int i = 0; i < 4; ++i) {
        const float* rowp = Winit + (size_t)pos * 64 + (size_t)(co_own + i) * 8;
        float4 a = *reinterpret_cast<const float4*>(rowp + co_own);
        float4 b = *reinterpret_cast<const float4*>(rowp + co_oth);
        W[i][0] = a.x; W[i][1] = a.y; W[i][2] = a.z; W[i][3] = a.w;
        W[i][4] = b.x; W[i][5] = b.y; W[i][6] = b.z; W[i][7] = b.w;
        W[i][i] = 0.0f;                  // local diag == global diag
    }

    const float stim = stim_in[pos];

    for (int st = 0; st < steps; ++st) {
        float nb[4][4];
        #pragma unroll
        for (int i = 0; i < 4; ++i) {
            float s0 = 0.f, s1 = 0.f, s2 = 0.f, s3 = 0.f, tw = 0.f;
            #pragma unroll
            for (int j = 0; j < 8; ++j) {
                float w = W[i][j];
                s0 += w * h[j][0];
                s1 += w * h[j][1];
                s2 += w * h[j][2];
                s3 += w * h[j][3];
                tw += w;
            }
            float inv = __builtin_amdgcn_rcpf(tw + 1e-8f);
            nb[i][0] = s0 * inv; nb[i][1] = s1 * inv;
            nb[i][2] = s2 * inv; nb[i][3] = s3 * inv;
        }
        #pragma unroll
        for (int i = 0; i < 4; ++i) {
            float E = h[i][0], P = h[i][1], G = h[i][2], L = h[i][3];
            float En = nb[i][0], Pn = nb[i][1], Gn = nb[i][2], Ln = nb[i][3];
            float E_new = clamp01(E + 0.3f * stim - 0.4f * P - 0.2f * G);
            float P_new = clamp01(P + 0.5f * stim + 0.3f * (Pn - P) - 0.2f * E);
            float G_new = clamp01(G + 0.4f * E * (1.0f - P) + 0.2f * (Gn - G) - 0.3f * P);
            float good  = 0.5f * En + 0.5f * Gn;
            float L_new = clamp01(L + 0.4f * good + 0.3f * (Ln - L) - 0.3f * P);
            h[i][0] = E_new; h[i][1] = P_new; h[i][2] = G_new; h[i][3] = L_new;
        }
        // mirror partner's updated half
        #pragma unroll
        for (int b = 0; b < 4; ++b)
            #pragma unroll
            for (int c = 0; c < 4; ++c)
                h[4 + b][c] = __shfl_xor(h[b][c], 1, 64);
        // W update: own rows only. intra-half pairs update both sides;
        // cross-half only own side (partner computes its own).
        #pragma unroll
        for (int i = 0; i < 4; ++i) {
            #pragma unroll
            for (int j = i + 1; j < 8; ++j) {
                float d0 = h[i][0] - h[j][0];
                float d1 = h[i][1] - h[j][1];
                float d2 = h[i][2] - h[j][2];
                float d3 = h[i][3] - h[j][3];
                float q = d0 * d0 + d1 * d1 + d2 * d2 + d3 * d3;
                float dist = __builtin_amdgcn_sqrtf(q);    // sqrt(0)=0: guard-free
                float inc = 0.1f * (0.5f * (h[i][3] + h[j][3])) * dist;
                W[i][j] = clamp01(W[i][j] + inc - 0.05f * W[i][j]);
                if (j < 4)
                    W[j][i] = clamp01(W[j][i] + inc - 0.05f * W[j][i]);
            }
        }
    }

    // ---- wave-private LDS transpose (8 KB/wave, no barriers: exclusive region)
    __shared__ float xpose[4][2048];
    const int w = tid >> 6;
    const int l = tid & 63;
    float* buf = xpose[w];
    const int posBase = blockIdx.x * 128 + w * 32;   // 32 positions per wave

    // W: flat = (l>>1)*64 + globalfeat = l*32 + (i*8+gc);  gc = global col
    #pragma unroll
    for (int i = 0; i < 4; ++i) {
        #pragma unroll
        for (int lb = 0; lb < 8; ++lb) {
            const int gc = (lb < 4) ? (co_own + lb) : (co_oth + lb - 4);
            const int kg = i * 8 + gc;
            buf[l * 32 + (kg ^ (l & 31))] = W[i][lb];
        }
    }
    {
        float* dst = out_W + (size_t)posBase * 64;
        #pragma unroll
        for (int i2 = 0; i2 < 32; ++i2) {
            const int r = i2 * 2 + (l >> 5);
            dst[i2 * 64 + l] = buf[r * 32 + ((l & 31) ^ (r & 31))];  // 256B/inst
        }
    }
    // h: flat = l*16 + k, k = i*4+ch (global feat = sub*16+k via address)
    #pragma unroll
    for (int i = 0; i < 4; ++i) {
        #pragma unroll
        for (int c = 0; c < 4; ++c) {
            const int k = i * 4 + c;
            buf[l * 16 + (k ^ ((l >> 1) & 15))] = h[i][c];
        }
    }
    {
        float* dst = out_h + (size_t)posBase * 32;
        #pragma unroll
        for (int i2 = 0; i2 < 16; ++i2) {
            const int r = i2 * 4 + (l >> 4);
            const int s = (r >> 1) & 15;
            dst[i2 * 64 + l] = buf[r * 16 + ((l & 15) ^ s)];         // 256B/inst
        }
    }
}

// ---------------------------------------------------------------------------
// Kernel B: emb = phys @ lin_w^T + lin_b via f16 MFMA.  (unchanged, ~24 us,
// near its 134 MB write floor)
// ---------------------------------------------------------------------------
__global__ __launch_bounds__(256, 4) void einsum_mfma_kernel(
    const float* __restrict__ hsrc,
    const float* __restrict__ wsrc,
    const _Float16* __restrict__ Bpre,
    const float* __restrict__ lin_b,
    float* __restrict__ out_emb)
{
    __shared__ float Cbuf[64 * 132];
    const int tid = threadIdx.x;
    const int w = tid >> 6, l = tid & 63;
    const int pos0 = blockIdx.x * 64;

    const int arow = pos0 + w * 16 + (l & 15);
    const int koff = 4 * (l >> 4);
    half8 afr[3];
    {
        const float* s0 = hsrc + (size_t)arow * 32 + koff;
        float4 lo = *reinterpret_cast<const float4*>(s0);
        float4 hi = *reinterpret_cast<const float4*>(s0 + 16);
        afr[0][0] = (_Float16)lo.x; afr[0][1] = (_Float16)lo.y;
        afr[0][2] = (_Float16)lo.z; afr[0][3] = (_Float16)lo.w;
        afr[0][4] = (_Float16)hi.x; afr[0][5] = (_Float16)hi.y;
        afr[0][6] = (_Float16)hi.z; afr[0][7] = (_Float16)hi.w;
        #pragma unroll
        for (int ks = 1; ks < 3; ++ks) {
            const float* s = wsrc + (size_t)arow * 64 + (ks - 1) * 32 + koff;
            float4 a = *reinterpret_cast<const float4*>(s);
            float4 b = *reinterpret_cast<const float4*>(s + 16);
            afr[ks][0] = (_Float16)a.x; afr[ks][1] = (_Float16)a.y;
            afr[ks][2] = (_Float16)a.z; afr[ks][3] = (_Float16)a.w;
            afr[ks][4] = (_Float16)b.x; afr[ks][5] = (_Float16)b.y;
            afr[ks][6] = (_Float16)b.z; afr[ks][7] = (_Float16)b.w;
        }
    }

    f32x4 acc[16];
    #pragma unroll
    for (int nbv = 0; nbv < 16; ++nbv) acc[nbv] = (f32x4){0.f, 0.f, 0.f, 0.f};
    #pragma unroll
    for (int ks = 0; ks < 3; ++ks) {
        #pragma unroll
        for (int nbv = 0; nbv < 16; ++nbv) {
            half8 b = *reinterpret_cast<const half8*>(Bpre + (size_t)((ks * 16 + nbv) * 64 + l) * 8);
            acc[nbv] = __builtin_amdgcn_mfma_f32_16x16x32_f16(afr[ks], b, acc[nbv], 0, 0, 0);
        }
    }

    #pragma unroll
    for (int c = 0; c < 2; ++c) {
        #pragma unroll
        for (int nn = 0; nn < 8; ++nn) {
            const int nbv = c * 8 + nn;
            #pragma unroll
            for (int r = 0; r < 4; ++r) {
                const int row = w * 16 + 4 * (l >> 4) + r;
                Cbuf[row * 132 + nn * 16 + (l & 15)] = acc[nbv][r];
            }
        }
        __syncthreads();
        const float4 biasv = reinterpret_cast<const float4*>(lin_b)[c * 32 + (l & 31)];
        #pragma unroll
        for (int rep = 0; rep < 8; ++rep) {
            const int row = w * 16 + rep * 2 + (l >> 5);
            float4 v = *reinterpret_cast<const float4*>(Cbuf + row * 132 + (l & 31) * 4);
            v.x += biasv.x; v.y += biasv.y; v.z += biasv.z; v.w += biasv.w;
            *reinterpret_cast<float4*>(out_emb + (size_t)(pos0 + row) * DM + c * 128 + (l & 31) * 4) = v;
        }
        __syncthreads();
    }
}

extern "C" void kernel_launch(void* const* d_in, const int* in_sizes, int n_in,
                              void* d_out, int out_size, void* d_ws, size_t ws_size,
                              hipStream_t stream) {
    const int*   bits  = (const int*)d_in[0];
    const float* stim  = (const float*)d_in[1];
    const float* Winit = (const float*)d_in[2];
    const float* lin_w = (const float*)d_in[3];
    const float* lin_b = (const float*)d_in[4];
    const int*   steps = (const int*)d_in[5];

    const int npos = in_sizes[1];   // B*S = 131072

    float* out_emb = (float*)d_out;
    float* out_h   = out_emb + (size_t)npos * DM;
    float* out_W   = out_h + (size_t)npos * 32;
    _Float16* Bpre = (_Float16*)d_ws;            // 48 KB fragment buffer

    hipLaunchKernelGGL(bprep_kernel, dim3(12), dim3(256), 0, stream, lin_w, Bpre);
    hipLaunchKernelGGL(bio_sim_kernel, dim3(npos / 128), dim3(256), 0, stream,
                       bits, stim, Winit, steps, out_h, out_W, npos);
    hipLaunchKernelGGL(einsum_mfma_kernel, dim3(npos / 64), dim3(256), 0, stream,
                       out_h, out_W, Bpre, lin_b, out_emb);
}

// Round 11
// 84.998 us; speedup vs baseline: 1.2561x; 1.2561x over previous
//
#include <hip/hip_runtime.h>

#define NB 8
#define DM 256
#define FD 96
#define SLD 104   // f16 stride of phys staging row (208B = 13*16, 16B-aligned)

using half8 = _Float16 __attribute__((ext_vector_type(8)));
using half4 = _Float16 __attribute__((ext_vector_type(4)));
using f32x4 = float __attribute__((ext_vector_type(4)));

__device__ __forceinline__ float clamp01(float x) { return fminf(fmaxf(x, 0.0f), 1.0f); }

// ---------------------------------------------------------------------------
// Kernel 0: precompute B = lin_w^T as f16 MFMA fragments into d_ws (48 KB).
// Fragment map (16x16x32): elem j <-> k = 4*(l>>4)+(j&3)+16*(j>>2), col = l&15.
// ---------------------------------------------------------------------------
__global__ void bprep_kernel(const float* __restrict__ lin_w,
                             _Float16* __restrict__ Bpre)
{
    const int fb = blockIdx.x * 256 + threadIdx.x;     // 0..3071
    const int ks = fb >> 10, nbv = (fb >> 6) & 15, ll = fb & 63;
    const float* lwrow = lin_w + (size_t)(nbv * 16 + (ll & 15)) * FD
                               + (ks * 32 + 4 * (ll >> 4));
    float4 lo = *reinterpret_cast<const float4*>(lwrow);
    float4 hi = *reinterpret_cast<const float4*>(lwrow + 16);
    half8 v;
    v[0] = (_Float16)lo.x; v[1] = (_Float16)lo.y; v[2] = (_Float16)lo.z; v[3] = (_Float16)lo.w;
    v[4] = (_Float16)hi.x; v[5] = (_Float16)hi.y; v[6] = (_Float16)hi.z; v[7] = (_Float16)hi.w;
    *reinterpret_cast<half8*>(Bpre + (size_t)fb * 8) = v;
}

// ---------------------------------------------------------------------------
// Fused kernel: 2-lane-per-position sim (r9/r10 math, proven) -> f16 phys
// staging in LDS -> h/W f32 outputs from staging -> in-block f16 MFMA einsum.
// Block = 256 threads / 128 positions. LDS = 26.6 KB. launch_bounds (256,2):
// 256-VGPR cap = zero spill risk (r9 vs r10: occupancy 2 vs 4 waves/SIMD
// made no difference, so safety wins).
// ---------------------------------------------------------------------------
__global__ __launch_bounds__(256, 2) void fused_kernel(
    const int* __restrict__ bits,
    const float* __restrict__ stim_in,
    const float* __restrict__ Winit,
    const int* __restrict__ steps_ptr,
    const _Float16* __restrict__ Bpre,
    const float* __restrict__ lin_b,
    float* __restrict__ out_emb,
    float* __restrict__ out_h,
    float* __restrict__ out_W)
{
    __shared__ __align__(16) _Float16 S[128 * SLD];   // phys staging [128 pos][96+pad]

    const int tid  = threadIdx.x;
    const int pos0 = blockIdx.x * 128;
    const int p    = tid >> 1;            // position within block
    const int pos  = pos0 + p;
    const int sub  = tid & 1;
    const int steps = steps_ptr[0];

    float h[8][4];   // local order: 0..3 own half, 4..7 partner half
    float W[4][8];   // own 4 rows x 8 local cols (own-half cols first)

    // ---- decode own 4 blocks
    const int4* bp = reinterpret_cast<const int4*>(bits + (size_t)pos * 64 + sub * 32);
    #pragma unroll
    for (int b = 0; b < 4; ++b) {
        int4 lo = bp[2 * b + 0];
        int4 hi = bp[2 * b + 1];
        h[b][0] = (float)(lo.x * 2 + lo.y) / 3.0f;
        h[b][1] = (float)(lo.z * 2 + lo.w) / 3.0f;
        h[b][2] = (float)(hi.x * 2 + hi.y) / 3.0f;
        h[b][3] = (float)(hi.z * 2 + hi.w) / 3.0f;
    }
    #pragma unroll
    for (int b = 0; b < 4; ++b)
        #pragma unroll
        for (int c = 0; c < 4; ++c)
            h[4 + b][c] = __shfl_xor(h[b][c], 1, 64);

    const int co_own = sub * 4;
    const int co_oth = 4 - sub * 4;
    #pragma unroll
    for (int i = 0; i < 4; ++i) {
        const float* rowp = Winit + (size_t)pos * 64 + (size_t)(co_own + i) * 8;
        float4 a = *reinterpret_cast<const float4*>(rowp + co_own);
        float4 b = *reinterpret_cast<const float4*>(rowp + co_oth);
        W[i][0] = a.x; W[i][1] = a.y; W[i][2] = a.z; W[i][3] = a.w;
        W[i][4] = b.x; W[i][5] = b.y; W[i][6] = b.z; W[i][7] = b.w;
        W[i][i] = 0.0f;
    }

    const float stim = stim_in[pos];

    for (int st = 0; st < steps; ++st) {
        float nb[4][4];
        #pragma unroll
        for (int i = 0; i < 4; ++i) {
            float s0 = 0.f, s1 = 0.f, s2 = 0.f, s3 = 0.f, tw = 0.f;
            #pragma unroll
            for (int j = 0; j < 8; ++j) {
                float w = W[i][j];
                s0 += w * h[j][0];
                s1 += w * h[j][1];
                s2 += w * h[j][2];
                s3 += w * h[j][3];
                tw += w;
            }
            float inv = __builtin_amdgcn_rcpf(tw + 1e-8f);
            nb[i][0] = s0 * inv; nb[i][1] = s1 * inv;
            nb[i][2] = s2 * inv; nb[i][3] = s3 * inv;
        }
        #pragma unroll
        for (int i = 0; i < 4; ++i) {
            float E = h[i][0], P = h[i][1], G = h[i][2], L = h[i][3];
            float En = nb[i][0], Pn = nb[i][1], Gn = nb[i][2], Ln = nb[i][3];
            float E_new = clamp01(E + 0.3f * stim - 0.4f * P - 0.2f * G);
            float P_new = clamp01(P + 0.5f * stim + 0.3f * (Pn - P) - 0.2f * E);
            float G_new = clamp01(G + 0.4f * E * (1.0f - P) + 0.2f * (Gn - G) - 0.3f * P);
            float good  = 0.5f * En + 0.5f * Gn;
            float L_new = clamp01(L + 0.4f * good + 0.3f * (Ln - L) - 0.3f * P);
            h[i][0] = E_new; h[i][1] = P_new; h[i][2] = G_new; h[i][3] = L_new;
        }
        #pragma unroll
        for (int b = 0; b < 4; ++b)
            #pragma unroll
            for (int c = 0; c < 4; ++c)
                h[4 + b][c] = __shfl_xor(h[b][c], 1, 64);
        #pragma unroll
        for (int i = 0; i < 4; ++i) {
            #pragma unroll
            for (int j = i + 1; j < 8; ++j) {
                float d0 = h[i][0] - h[j][0];
                float d1 = h[i][1] - h[j][1];
                float d2 = h[i][2] - h[j][2];
                float d3 = h[i][3] - h[j][3];
                float q = d0 * d0 + d1 * d1 + d2 * d2 + d3 * d3;
                float dist = __builtin_amdgcn_sqrtf(q);
                float inc = 0.1f * (0.5f * (h[i][3] + h[j][3])) * dist;
                W[i][j] = clamp01(W[i][j] + inc - 0.05f * W[i][j]);
                if (j < 4)
                    W[j][i] = clamp01(W[j][i] + inc - 0.05f * W[j][i]);
            }
        }
    }

    // ---- stage phys as f16 into S: feats 0..31 = h (global order), 32..95 = W
    {
        _Float16* sp = S + p * SLD;
        // own h half -> feats sub*16 .. +15 (global feat = (sub*4+b)*4+c)
        half8 v0, v1;
        #pragma unroll
        for (int c = 0; c < 4; ++c) {
            v0[c]     = (_Float16)h[0][c];
            v0[4 + c] = (_Float16)h[1][c];
            v1[c]     = (_Float16)h[2][c];
            v1[4 + c] = (_Float16)h[3][c];
        }
        *reinterpret_cast<half8*>(sp + sub * 16)     = v0;
        *reinterpret_cast<half8*>(sp + sub * 16 + 8) = v1;
        // own W rows (global rows co_own+i), global column order
        #pragma unroll
        for (int i = 0; i < 4; ++i) {
            half8 wv;
            #pragma unroll
            for (int gc = 0; gc < 8; ++gc) {
                // local col: sub==0 -> gc; sub==1 -> (gc+4)&7
                float v = (sub == 0) ? W[i][gc] : W[i][(gc + 4) & 7];
                wv[gc] = (_Float16)v;
            }
            *reinterpret_cast<half8*>(sp + 32 + (co_own + i) * 8) = wv;
        }
    }
    __syncthreads();

    // ---- h/W f32 outputs from staging (coalesced 256B stores; f16 rounding
    //      adds <=4.9e-4 abs, threshold 3.84e-2)
    #pragma unroll
    for (int i = 0; i < 16; ++i) {
        const int flat = i * 256 + tid;
        out_h[(size_t)pos0 * 32 + flat] = (float)S[(flat >> 5) * SLD + (flat & 31)];
    }
    #pragma unroll
    for (int i = 0; i < 32; ++i) {
        const int flat = i * 256 + tid;
        out_W[(size_t)pos0 * 64 + flat] = (float)S[(flat >> 6) * SLD + 32 + (flat & 63)];
    }

    // ---- einsum: 2 M-tiles of 64 rows; A from S, B from Bpre, C direct-store
    const int w = tid >> 6, l = tid & 63;
    float blin[16];
    #pragma unroll
    for (int nbv = 0; nbv < 16; ++nbv)
        blin[nbv] = lin_b[nbv * 16 + (l & 15)];

    #pragma unroll
    for (int t = 0; t < 2; ++t) {
        const int r = t * 64 + w * 16 + (l & 15);
        const int k0q = 4 * (l >> 4);
        half8 afr[3];
        #pragma unroll
        for (int ks = 0; ks < 3; ++ks) {
            half4 lo = *reinterpret_cast<const half4*>(S + r * SLD + ks * 32 + k0q);
            half4 hi = *reinterpret_cast<const half4*>(S + r * SLD + ks * 32 + 16 + k0q);
            afr[ks] = __builtin_shufflevector(lo, hi, 0, 1, 2, 3, 4, 5, 6, 7);
        }
        f32x4 acc[16];
        #pragma unroll
        for (int nbv = 0; nbv < 16; ++nbv) acc[nbv] = (f32x4){0.f, 0.f, 0.f, 0.f};
        #pragma unroll
        for (int ks = 0; ks < 3; ++ks) {
            #pragma unroll
            for (int nbv = 0; nbv < 16; ++nbv) {
                half8 b = *reinterpret_cast<const half8*>(Bpre + (size_t)((ks * 16 + nbv) * 64 + l) * 8);
                acc[nbv] = __builtin_amdgcn_mfma_f32_16x16x32_f16(afr[ks], b, acc[nbv], 0, 0, 0);
            }
        }
        // C: row = pos0 + t*64 + w*16 + 4*(l>>4) + reg, col = nbv*16 + (l&15)
        // reg-outer/nbv-inner: each 16-inst burst densely covers 4 rows x 1KB
        #pragma unroll
        for (int reg = 0; reg < 4; ++reg) {
            float* outp = out_emb + (size_t)(pos0 + t * 64 + w * 16 + 4 * (l >> 4) + reg) * DM + (l & 15);
            #pragma unroll
            for (int nbv = 0; nbv < 16; ++nbv)
                outp[nbv * 16] = acc[nbv][reg] + blin[nbv];
        }
    }
}

extern "C" void kernel_launch(void* const* d_in, const int* in_sizes, int n_in,
                              void* d_out, int out_size, void* d_ws, size_t ws_size,
                              hipStream_t stream) {
    const int*   bits  = (const int*)d_in[0];
    const float* stim  = (const float*)d_in[1];
    const float* Winit = (const float*)d_in[2];
    const float* lin_w = (const float*)d_in[3];
    const float* lin_b = (const float*)d_in[4];
    const int*   steps = (const int*)d_in[5];

    const int npos = in_sizes[1];   // B*S = 131072

    float* out_emb = (float*)d_out;
    float* out_h   = out_emb + (size_t)npos * DM;
    float* out_W   = out_h + (size_t)npos * 32;
    _Float16* Bpre = (_Float16*)d_ws;            // 48 KB fragment buffer

    hipLaunchKernelGGL(bprep_kernel, dim3(12), dim3(256), 0, stream, lin_w, Bpre);
    hipLaunchKernelGGL(fused_kernel, dim3(npos / 128), dim3(256), 0, stream,
                       bits, stim, Winit, steps, Bpre, lin_b,
                       out_emb, out_h, out_W);
}

// Round 12
// 83.848 us; speedup vs baseline: 1.2733x; 1.0137x over previous
//
#include <hip/hip_runtime.h>

#define NB 8
#define DM 256
#define FD 96
#define SLD 104   // f16 stride of phys staging row (208B = 13*16, 16B-aligned)

using half8 = _Float16 __attribute__((ext_vector_type(8)));
using half4 = _Float16 __attribute__((ext_vector_type(4)));
using f32x4 = float __attribute__((ext_vector_type(4)));

__device__ __forceinline__ float clamp01(float x) { return fminf(fmaxf(x, 0.0f), 1.0f); }

// ---------------------------------------------------------------------------
// Kernel 0: precompute B = lin_w^T as f16 MFMA fragments into d_ws (48 KB).
// ---------------------------------------------------------------------------
__global__ void bprep_kernel(const float* __restrict__ lin_w,
                             _Float16* __restrict__ Bpre)
{
    const int fb = blockIdx.x * 256 + threadIdx.x;     // 0..3071
    const int ks = fb >> 10, nbv = (fb >> 6) & 15, ll = fb & 63;
    const float* lwrow = lin_w + (size_t)(nbv * 16 + (ll & 15)) * FD
                               + (ks * 32 + 4 * (ll >> 4));
    float4 lo = *reinterpret_cast<const float4*>(lwrow);
    float4 hi = *reinterpret_cast<const float4*>(lwrow + 16);
    half8 v;
    v[0] = (_Float16)lo.x; v[1] = (_Float16)lo.y; v[2] = (_Float16)lo.z; v[3] = (_Float16)lo.w;
    v[4] = (_Float16)hi.x; v[5] = (_Float16)hi.y; v[6] = (_Float16)hi.z; v[7] = (_Float16)hi.w;
    *reinterpret_cast<half8*>(Bpre + (size_t)fb * 8) = v;
}

// ---------------------------------------------------------------------------
// Fused kernel (r11 structure). Single change vs r11: C is flushed through a
// padded LDS transpose (512B-contiguous float4 stores, the r4-r10 proven
// pattern) instead of per-lane scalar dword stores at 64B stride, which risk
// partial-line RMW on the whole 134 MB emb tensor. LDS: S (26.6 KB) and
// Cbuf (33.8 KB) share one 33.8 KB allocation; all S consumers (h/W readback,
// A-fragment loads for BOTH tiles) complete before the overlay barrier.
// ---------------------------------------------------------------------------
__global__ __launch_bounds__(256, 2) void fused_kernel(
    const int* __restrict__ bits,
    const float* __restrict__ stim_in,
    const float* __restrict__ Winit,
    const int* __restrict__ steps_ptr,
    const _Float16* __restrict__ Bpre,
    const float* __restrict__ lin_b,
    float* __restrict__ out_emb,
    float* __restrict__ out_h,
    float* __restrict__ out_W)
{
    __shared__ __align__(16) char smem[64 * 132 * 4];   // 33792 B union
    _Float16* S    = reinterpret_cast<_Float16*>(smem); // [128][SLD] staging
    float*    Cbuf = reinterpret_cast<float*>(smem);    // [64][132] overlay

    const int tid  = threadIdx.x;
    const int pos0 = blockIdx.x * 128;
    const int p    = tid >> 1;
    const int pos  = pos0 + p;
    const int sub  = tid & 1;
    const int steps = steps_ptr[0];

    float h[8][4];   // local order: 0..3 own half, 4..7 partner half
    float W[4][8];   // own 4 rows x 8 local cols (own-half cols first)

    // ---- decode own 4 blocks
    const int4* bp = reinterpret_cast<const int4*>(bits + (size_t)pos * 64 + sub * 32);
    #pragma unroll
    for (int b = 0; b < 4; ++b) {
        int4 lo = bp[2 * b + 0];
        int4 hi = bp[2 * b + 1];
        h[b][0] = (float)(lo.x * 2 + lo.y) / 3.0f;
        h[b][1] = (float)(lo.z * 2 + lo.w) / 3.0f;
        h[b][2] = (float)(hi.x * 2 + hi.y) / 3.0f;
        h[b][3] = (float)(hi.z * 2 + hi.w) / 3.0f;
    }
    #pragma unroll
    for (int b = 0; b < 4; ++b)
        #pragma unroll
        for (int c = 0; c < 4; ++c)
            h[4 + b][c] = __shfl_xor(h[b][c], 1, 64);

    const int co_own = sub * 4;
    const int co_oth = 4 - sub * 4;
    #pragma unroll
    for (int i = 0; i < 4; ++i) {
        const float* rowp = Winit + (size_t)pos * 64 + (size_t)(co_own + i) * 8;
        float4 a = *reinterpret_cast<const float4*>(rowp + co_own);
        float4 b = *reinterpret_cast<const float4*>(rowp + co_oth);
        W[i][0] = a.x; W[i][1] = a.y; W[i][2] = a.z; W[i][3] = a.w;
        W[i][4] = b.x; W[i][5] = b.y; W[i][6] = b.z; W[i][7] = b.w;
        W[i][i] = 0.0f;
    }

    const float stim = stim_in[pos];

    for (int st = 0; st < steps; ++st) {
        float nb[4][4];
        #pragma unroll
        for (int i = 0; i < 4; ++i) {
            float s0 = 0.f, s1 = 0.f, s2 = 0.f, s3 = 0.f, tw = 0.f;
            #pragma unroll
            for (int j = 0; j < 8; ++j) {
                float w = W[i][j];
                s0 += w * h[j][0];
                s1 += w * h[j][1];
                s2 += w * h[j][2];
                s3 += w * h[j][3];
                tw += w;
            }
            float inv = __builtin_amdgcn_rcpf(tw + 1e-8f);
            nb[i][0] = s0 * inv; nb[i][1] = s1 * inv;
            nb[i][2] = s2 * inv; nb[i][3] = s3 * inv;
        }
        #pragma unroll
        for (int i = 0; i < 4; ++i) {
            float E = h[i][0], P = h[i][1], G = h[i][2], L = h[i][3];
            float En = nb[i][0], Pn = nb[i][1], Gn = nb[i][2], Ln = nb[i][3];
            float E_new = clamp01(E + 0.3f * stim - 0.4f * P - 0.2f * G);
            float P_new = clamp01(P + 0.5f * stim + 0.3f * (Pn - P) - 0.2f * E);
            float G_new = clamp01(G + 0.4f * E * (1.0f - P) + 0.2f * (Gn - G) - 0.3f * P);
            float good  = 0.5f * En + 0.5f * Gn;
            float L_new = clamp01(L + 0.4f * good + 0.3f * (Ln - L) - 0.3f * P);
            h[i][0] = E_new; h[i][1] = P_new; h[i][2] = G_new; h[i][3] = L_new;
        }
        #pragma unroll
        for (int b = 0; b < 4; ++b)
            #pragma unroll
            for (int c = 0; c < 4; ++c)
                h[4 + b][c] = __shfl_xor(h[b][c], 1, 64);
        #pragma unroll
        for (int i = 0; i < 4; ++i) {
            #pragma unroll
            for (int j = i + 1; j < 8; ++j) {
                float d0 = h[i][0] - h[j][0];
                float d1 = h[i][1] - h[j][1];
                float d2 = h[i][2] - h[j][2];
                float d3 = h[i][3] - h[j][3];
                float q = d0 * d0 + d1 * d1 + d2 * d2 + d3 * d3;
                float dist = __builtin_amdgcn_sqrtf(q);
                float inc = 0.1f * (0.5f * (h[i][3] + h[j][3])) * dist;
                W[i][j] = clamp01(W[i][j] + inc - 0.05f * W[i][j]);
                if (j < 4)
                    W[j][i] = clamp01(W[j][i] + inc - 0.05f * W[j][i]);
            }
        }
    }

    // ---- stage phys as f16 into S: feats 0..31 = h (global order), 32..95 = W
    {
        _Float16* sp = S + p * SLD;
        half8 v0, v1;
        #pragma unroll
        for (int c = 0; c < 4; ++c) {
            v0[c]     = (_Float16)h[0][c];
            v0[4 + c] = (_Float16)h[1][c];
            v1[c]     = (_Float16)h[2][c];
            v1[4 + c] = (_Float16)h[3][c];
        }
        *reinterpret_cast<half8*>(sp + sub * 16)     = v0;
        *reinterpret_cast<half8*>(sp + sub * 16 + 8) = v1;
        #pragma unroll
        for (int i = 0; i < 4; ++i) {
            half8 wv;
            #pragma unroll
            for (int gc = 0; gc < 8; ++gc) {
                float v = (sub == 0) ? W[i][gc] : W[i][(gc + 4) & 7];
                wv[gc] = (_Float16)v;
            }
            *reinterpret_cast<half8*>(sp + 32 + (co_own + i) * 8) = wv;
        }
    }
    __syncthreads();

    // ---- h/W f32 outputs from staging (coalesced 256B stores)
    #pragma unroll
    for (int i = 0; i < 16; ++i) {
        const int flat = i * 256 + tid;
        out_h[(size_t)pos0 * 32 + flat] = (float)S[(flat >> 5) * SLD + (flat & 31)];
    }
    #pragma unroll
    for (int i = 0; i < 32; ++i) {
        const int flat = i * 256 + tid;
        out_W[(size_t)pos0 * 64 + flat] = (float)S[(flat >> 6) * SLD + 32 + (flat & 63)];
    }

    // ---- load A fragments for BOTH tiles before S is overlaid by Cbuf
    const int w = tid >> 6, l = tid & 63;
    const int k0q = 4 * (l >> 4);
    half8 afr[2][3];
    #pragma unroll
    for (int t = 0; t < 2; ++t) {
        const int r = t * 64 + w * 16 + (l & 15);
        #pragma unroll
        for (int ks = 0; ks < 3; ++ks) {
            half4 lo = *reinterpret_cast<const half4*>(S + r * SLD + ks * 32 + k0q);
            half4 hi = *reinterpret_cast<const half4*>(S + r * SLD + ks * 32 + 16 + k0q);
            afr[t][ks] = __builtin_shufflevector(lo, hi, 0, 1, 2, 3, 4, 5, 6, 7);
        }
    }
    __syncthreads();   // all S reads done; smem becomes Cbuf

    // ---- einsum per tile; C via padded-LDS transpose, 512B float4 stores
    #pragma unroll
    for (int t = 0; t < 2; ++t) {
        f32x4 acc[16];
        #pragma unroll
        for (int nbv = 0; nbv < 16; ++nbv) acc[nbv] = (f32x4){0.f, 0.f, 0.f, 0.f};
        #pragma unroll
        for (int ks = 0; ks < 3; ++ks) {
            #pragma unroll
            for (int nbv = 0; nbv < 16; ++nbv) {
                half8 b = *reinterpret_cast<const half8*>(Bpre + (size_t)((ks * 16 + nbv) * 64 + l) * 8);
                acc[nbv] = __builtin_amdgcn_mfma_f32_16x16x32_f16(afr[t][ks], b, acc[nbv], 0, 0, 0);
            }
        }
        #pragma unroll
        for (int c = 0; c < 2; ++c) {
            #pragma unroll
            for (int nn = 0; nn < 8; ++nn) {
                const int nbv = c * 8 + nn;
                #pragma unroll
                for (int r = 0; r < 4; ++r) {
                    const int row = w * 16 + 4 * (l >> 4) + r;
                    Cbuf[row * 132 + nn * 16 + (l & 15)] = acc[nbv][r];
                }
            }
            __syncthreads();
            const float4 biasv = reinterpret_cast<const float4*>(lin_b)[c * 32 + (l & 31)];
            #pragma unroll
            for (int rep = 0; rep < 8; ++rep) {
                const int row = w * 16 + rep * 2 + (l >> 5);
                float4 v = *reinterpret_cast<const float4*>(Cbuf + row * 132 + (l & 31) * 4);
                v.x += biasv.x; v.y += biasv.y; v.z += biasv.z; v.w += biasv.w;
                *reinterpret_cast<float4*>(out_emb + (size_t)(pos0 + t * 64 + row) * DM
                                           + c * 128 + (l & 31) * 4) = v;
            }
            __syncthreads();
        }
    }
}

extern "C" void kernel_launch(void* const* d_in, const int* in_sizes, int n_in,
                              void* d_out, int out_size, void* d_ws, size_t ws_size,
                              hipStream_t stream) {
    const int*   bits  = (const int*)d_in[0];
    const float* stim  = (const float*)d_in[1];
    const float* Winit = (const float*)d_in[2];
    const float* lin_w = (const float*)d_in[3];
    const float* lin_b = (const float*)d_in[4];
    const int*   steps = (const int*)d_in[5];

    const int npos = in_sizes[1];   // B*S = 131072

    float* out_emb = (float*)d_out;
    float* out_h   = out_emb + (size_t)npos * DM;
    float* out_W   = out_h + (size_t)npos * 32;
    _Float16* Bpre = (_Float16*)d_ws;            // 48 KB fragment buffer

    hipLaunchKernelGGL(bprep_kernel, dim3(12), dim3(256), 0, stream, lin_w, Bpre);
    hipLaunchKernelGGL(fused_kernel, dim3(npos / 128), dim3(256), 0, stream,
                       bits, stim, Winit, steps, Bpre, lin_b,
                       out_emb, out_h, out_W);
}

// Round 14
// 75.246 us; speedup vs baseline: 1.4189x; 1.1143x over previous
//
#include <hip/hip_runtime.h>

#define NB 8
#define DM 256
#define FD 96
#define SLD 104   // f16 stride of phys staging row (208B = 13*16, 16B-aligned)

using half8 = _Float16 __attribute__((ext_vector_type(8)));
using half4 = _Float16 __attribute__((ext_vector_type(4)));
using f32x4 = float __attribute__((ext_vector_type(4)));
using f2    = float __attribute__((ext_vector_type(2)));

__device__ __forceinline__ float clamp01(float x) { return fminf(fmaxf(x, 0.0f), 1.0f); }

// ---------------------------------------------------------------------------
// Kernel 0: precompute B = lin_w^T as f16 MFMA fragments into d_ws (48 KB).
// ---------------------------------------------------------------------------
__global__ void bprep_kernel(const float* __restrict__ lin_w,
                             _Float16* __restrict__ Bpre)
{
    const int fb = blockIdx.x * 256 + threadIdx.x;     // 0..3071
    const int ks = fb >> 10, nbv = (fb >> 6) & 15, ll = fb & 63;
    const float* lwrow = lin_w + (size_t)(nbv * 16 + (ll & 15)) * FD
                               + (ks * 32 + 4 * (ll >> 4));
    float4 lo = *reinterpret_cast<const float4*>(lwrow);
    float4 hi = *reinterpret_cast<const float4*>(lwrow + 16);
    half8 v;
    v[0] = (_Float16)lo.x; v[1] = (_Float16)lo.y; v[2] = (_Float16)lo.z; v[3] = (_Float16)lo.w;
    v[4] = (_Float16)hi.x; v[5] = (_Float16)hi.y; v[6] = (_Float16)hi.z; v[7] = (_Float16)hi.w;
    *reinterpret_cast<half8*>(Bpre + (size_t)fb * 8) = v;
}

// ---------------------------------------------------------------------------
// Fused kernel. vs r12 (passed, 0.0156): ONLY order-preserving changes.
// - neigh matvec packed via elementwise_fma: per-channel fma chain j=0..7
//   ascending == r12's scalar fmac chain bit-for-bit.
// - tw: scalar sequential w0..w7 (r12's exact chain; f2 comps are free VGPRs).
// - h-update and W-update: verbatim r12 expressions/order (scalar).
// - h/W readback widened to ds_read_b64 + float4 stores (f16->f32 exact).
// Everything else byte-identical to r12.
// ---------------------------------------------------------------------------
__global__ __launch_bounds__(256, 2) void fused_kernel(
    const int* __restrict__ bits,
    const float* __restrict__ stim_in,
    const float* __restrict__ Winit,
    const int* __restrict__ steps_ptr,
    const _Float16* __restrict__ Bpre,
    const float* __restrict__ lin_b,
    float* __restrict__ out_emb,
    float* __restrict__ out_h,
    float* __restrict__ out_W)
{
    __shared__ __align__(16) char smem[64 * 132 * 4];   // 33792 B union
    _Float16* S    = reinterpret_cast<_Float16*>(smem); // [128][SLD] staging
    float*    Cbuf = reinterpret_cast<float*>(smem);    // [64][132] overlay

    const int tid  = threadIdx.x;
    const int pos0 = blockIdx.x * 128;
    const int p    = tid >> 1;
    const int pos  = pos0 + p;
    const int sub  = tid & 1;
    const int steps = steps_ptr[0];

    // local order: blocks 0..3 own half, 4..7 partner half
    f2 hA[8];        // (E,P) per block
    f2 hB[8];        // (G,L) per block
    f2 W2[4][4];     // own 4 rows x 4 local col-pairs

    // ---- decode own 4 blocks (r12 expressions)
    const int4* bp = reinterpret_cast<const int4*>(bits + (size_t)pos * 64 + sub * 32);
    #pragma unroll
    for (int b = 0; b < 4; ++b) {
        int4 lo = bp[2 * b + 0];
        int4 hi = bp[2 * b + 1];
        hA[b].x = (float)(lo.x * 2 + lo.y) / 3.0f;
        hA[b].y = (float)(lo.z * 2 + lo.w) / 3.0f;
        hB[b].x = (float)(hi.x * 2 + hi.y) / 3.0f;
        hB[b].y = (float)(hi.z * 2 + hi.w) / 3.0f;
    }
    #pragma unroll
    for (int b = 0; b < 4; ++b) {
        hA[4 + b].x = __shfl_xor(hA[b].x, 1, 64);
        hA[4 + b].y = __shfl_xor(hA[b].y, 1, 64);
        hB[4 + b].x = __shfl_xor(hB[b].x, 1, 64);
        hB[4 + b].y = __shfl_xor(hB[b].y, 1, 64);
    }

    const int co_own = sub * 4;
    const int co_oth = 4 - sub * 4;
    #pragma unroll
    for (int i = 0; i < 4; ++i) {
        const float* rowp = Winit + (size_t)pos * 64 + (size_t)(co_own + i) * 8;
        float4 a = *reinterpret_cast<const float4*>(rowp + co_own);
        float4 b = *reinterpret_cast<const float4*>(rowp + co_oth);
        W2[i][0] = (f2){a.x, a.y};
        W2[i][1] = (f2){a.z, a.w};
        W2[i][2] = (f2){b.x, b.y};
        W2[i][3] = (f2){b.z, b.w};
        if (i & 1) W2[i][i >> 1].y = 0.0f; else W2[i][i >> 1].x = 0.0f;  // diag
    }

    const float stim = stim_in[pos];

    for (int st = 0; st < steps; ++st) {
        // ---- neigh: packed fma chains, per-channel order j=0..7 (== r12)
        f2 nbA[4], nbB[4];
        #pragma unroll
        for (int i = 0; i < 4; ++i) {
            f2 sA = {0.f, 0.f}, sB = {0.f, 0.f};
            #pragma unroll
            for (int jc = 0; jc < 4; ++jc) {
                f2 wv = W2[i][jc];
                f2 w0 = {wv.x, wv.x};
                f2 w1 = {wv.y, wv.y};
                sA = __builtin_elementwise_fma(w0, hA[2 * jc],     sA);
                sA = __builtin_elementwise_fma(w1, hA[2 * jc + 1], sA);
                sB = __builtin_elementwise_fma(w0, hB[2 * jc],     sB);
                sB = __builtin_elementwise_fma(w1, hB[2 * jc + 1], sB);
            }
            // tw: scalar sequential w0..w7 (r12's exact chain)
            float tw = W2[i][0].x; tw += W2[i][0].y;
            tw += W2[i][1].x;      tw += W2[i][1].y;
            tw += W2[i][2].x;      tw += W2[i][2].y;
            tw += W2[i][3].x;      tw += W2[i][3].y;
            float inv = __builtin_amdgcn_rcpf(tw + 1e-8f);
            f2 inv2 = {inv, inv};
            nbA[i] = sA * inv2;
            nbB[i] = sB * inv2;
        }
        // ---- h update (verbatim r12 expressions on extracted scalars)
        #pragma unroll
        for (int i = 0; i < 4; ++i) {
            float E = hA[i].x, P = hA[i].y, G = hB[i].x, L = hB[i].y;
            float En = nbA[i].x, Pn = nbA[i].y, Gn = nbB[i].x, Ln = nbB[i].y;
            float E_new = clamp01(E + 0.3f * stim - 0.4f * P - 0.2f * G);
            float P_new = clamp01(P + 0.5f * stim + 0.3f * (Pn - P) - 0.2f * E);
            float G_new = clamp01(G + 0.4f * E * (1.0f - P) + 0.2f * (Gn - G) - 0.3f * P);
            float good  = 0.5f * En + 0.5f * Gn;
            float L_new = clamp01(L + 0.4f * good + 0.3f * (Ln - L) - 0.3f * P);
            hA[i] = (f2){E_new, P_new};
            hB[i] = (f2){G_new, L_new};
        }
        // mirror partner's updated half
        #pragma unroll
        for (int b = 0; b < 4; ++b) {
            hA[4 + b].x = __shfl_xor(hA[b].x, 1, 64);
            hA[4 + b].y = __shfl_xor(hA[b].y, 1, 64);
            hB[4 + b].x = __shfl_xor(hB[b].x, 1, 64);
            hB[4 + b].y = __shfl_xor(hB[b].y, 1, 64);
        }
        // ---- W update (verbatim r12 structure/expressions, scalar)
        #pragma unroll
        for (int i = 0; i < 4; ++i) {
            #pragma unroll
            for (int j = i + 1; j < 8; ++j) {
                float d0 = hA[i].x - hA[j].x;
                float d1 = hA[i].y - hA[j].y;
                float d2 = hB[i].x - hB[j].x;
                float d3 = hB[i].y - hB[j].y;
                float q = d0 * d0 + d1 * d1 + d2 * d2 + d3 * d3;
                float dist = __builtin_amdgcn_sqrtf(q);
                float inc = 0.1f * (0.5f * (hB[i].y + hB[j].y)) * dist;
                float wij = (j & 1) ? W2[i][j >> 1].y : W2[i][j >> 1].x;
                wij = clamp01(wij + inc - 0.05f * wij);
                if (j & 1) W2[i][j >> 1].y = wij; else W2[i][j >> 1].x = wij;
                if (j < 4) {
                    float wji = (i & 1) ? W2[j][i >> 1].y : W2[j][i >> 1].x;
                    wji = clamp01(wji + inc - 0.05f * wji);
                    if (i & 1) W2[j][i >> 1].y = wji; else W2[j][i >> 1].x = wji;
                }
            }
        }
    }

    // ---- stage phys as f16 into S (values identical to r12)
    {
        _Float16* sp = S + p * SLD;
        half8 v0, v1;
        v0[0] = (_Float16)hA[0].x; v0[1] = (_Float16)hA[0].y;
        v0[2] = (_Float16)hB[0].x; v0[3] = (_Float16)hB[0].y;
        v0[4] = (_Float16)hA[1].x; v0[5] = (_Float16)hA[1].y;
        v0[6] = (_Float16)hB[1].x; v0[7] = (_Float16)hB[1].y;
        v1[0] = (_Float16)hA[2].x; v1[1] = (_Float16)hA[2].y;
        v1[2] = (_Float16)hB[2].x; v1[3] = (_Float16)hB[2].y;
        v1[4] = (_Float16)hA[3].x; v1[5] = (_Float16)hA[3].y;
        v1[6] = (_Float16)hB[3].x; v1[7] = (_Float16)hB[3].y;
        *reinterpret_cast<half8*>(sp + sub * 16)     = v0;
        *reinterpret_cast<half8*>(sp + sub * 16 + 8) = v1;
        #pragma unroll
        for (int i = 0; i < 4; ++i) {
            half8 wv;
            #pragma unroll
            for (int gc = 0; gc < 8; ++gc) {
                const int lc0 = gc;
                const int lc1 = (gc + 4) & 7;
                float vs0 = (lc0 & 1) ? W2[i][lc0 >> 1].y : W2[i][lc0 >> 1].x;
                float vs1 = (lc1 & 1) ? W2[i][lc1 >> 1].y : W2[i][lc1 >> 1].x;
                wv[gc] = (_Float16)((sub == 0) ? vs0 : vs1);
            }
            *reinterpret_cast<half8*>(sp + 32 + (co_own + i) * 8) = wv;
        }
    }
    __syncthreads();

    // ---- h/W f32 outputs: wide readback (ds_read_b64 + float4, 1KB/wave-inst)
    #pragma unroll
    for (int i = 0; i < 4; ++i) {
        const int flat4 = i * 1024 + tid * 4;
        const int row = flat4 >> 5, feat = flat4 & 31;
        half4 v = *reinterpret_cast<const half4*>(S + row * SLD + feat);
        float4 o = make_float4((float)v[0], (float)v[1], (float)v[2], (float)v[3]);
        *reinterpret_cast<float4*>(out_h + (size_t)pos0 * 32 + flat4) = o;
    }
    #pragma unroll
    for (int i = 0; i < 8; ++i) {
        const int flat4 = i * 1024 + tid * 4;
        const int row = flat4 >> 6, feat = flat4 & 63;
        half4 v = *reinterpret_cast<const half4*>(S + row * SLD + 32 + feat);
        float4 o = make_float4((float)v[0], (float)v[1], (float)v[2], (float)v[3]);
        *reinterpret_cast<float4*>(out_W + (size_t)pos0 * 64 + flat4) = o;
    }

    // ---- load A fragments for BOTH tiles before S is overlaid by Cbuf
    const int w = tid >> 6, l = tid & 63;
    const int k0q = 4 * (l >> 4);
    half8 afr[2][3];
    #pragma unroll
    for (int t = 0; t < 2; ++t) {
        const int r = t * 64 + w * 16 + (l & 15);
        #pragma unroll
        for (int ks = 0; ks < 3; ++ks) {
            half4 lo = *reinterpret_cast<const half4*>(S + r * SLD + ks * 32 + k0q);
            half4 hi = *reinterpret_cast<const half4*>(S + r * SLD + ks * 32 + 16 + k0q);
            afr[t][ks] = __builtin_shufflevector(lo, hi, 0, 1, 2, 3, 4, 5, 6, 7);
        }
    }
    __syncthreads();   // all S reads done; smem becomes Cbuf

    // ---- einsum per tile; C via padded-LDS transpose, 512B float4 stores
    #pragma unroll
    for (int t = 0; t < 2; ++t) {
        f32x4 acc[16];
        #pragma unroll
        for (int nbv = 0; nbv < 16; ++nbv) acc[nbv] = (f32x4){0.f, 0.f, 0.f, 0.f};
        #pragma unroll
        for (int ks = 0; ks < 3; ++ks) {
            #pragma unroll
            for (int nbv = 0; nbv < 16; ++nbv) {
                half8 b = *reinterpret_cast<const half8*>(Bpre + (size_t)((ks * 16 + nbv) * 64 + l) * 8);
                acc[nbv] = __builtin_amdgcn_mfma_f32_16x16x32_f16(afr[t][ks], b, acc[nbv], 0, 0, 0);
            }
        }
        #pragma unroll
        for (int c = 0; c < 2; ++c) {
            #pragma unroll
            for (int nn = 0; nn < 8; ++nn) {
                const int nbv = c * 8 + nn;
                #pragma unroll
                for (int r = 0; r < 4; ++r) {
                    const int row = w * 16 + 4 * (l >> 4) + r;
                    Cbuf[row * 132 + nn * 16 + (l & 15)] = acc[nbv][r];
                }
            }
            __syncthreads();
            const float4 biasv = reinterpret_cast<const float4*>(lin_b)[c * 32 + (l & 31)];
            #pragma unroll
            for (int rep = 0; rep < 8; ++rep) {
                const int row = w * 16 + rep * 2 + (l >> 5);
                float4 v = *reinterpret_cast<const float4*>(Cbuf + row * 132 + (l & 31) * 4);
                v.x += biasv.x; v.y += biasv.y; v.z += biasv.z; v.w += biasv.w;
                *reinterpret_cast<float4*>(out_emb + (size_t)(pos0 + t * 64 + row) * DM
                                           + c * 128 + (l & 31) * 4) = v;
            }
            __syncthreads();
        }
    }
}

extern "C" void kernel_launch(void* const* d_in, const int* in_sizes, int n_in,
                              void* d_out, int out_size, void* d_ws, size_t ws_size,
                              hipStream_t stream) {
    const int*   bits  = (const int*)d_in[0];
    const float* stim  = (const float*)d_in[1];
    const float* Winit = (const float*)d_in[2];
    const float* lin_w = (const float*)d_in[3];
    const float* lin_b = (const float*)d_in[4];
    const int*   steps = (const int*)d_in[5];

    const int npos = in_sizes[1];   // B*S = 131072

    float* out_emb = (float*)d_out;
    float* out_h   = out_emb + (size_t)npos * DM;
    float* out_W   = out_h + (size_t)npos * 32;
    _Float16* Bpre = (_Float16*)d_ws;            // 48 KB fragment buffer

    hipLaunchKernelGGL(bprep_kernel, dim3(12), dim3(256), 0, stream, lin_w, Bpre);
    hipLaunchKernelGGL(fused_kernel, dim3(npos / 128), dim3(256), 0, stream,
                       bits, stim, Winit, steps, Bpre, lin_b,
                       out_emb, out_h, out_W);
}